// Round 19
// baseline (93.719 us; speedup 1.0000x reference)
//
#include <hip/hip_runtime.h>
#include <hip/hip_bf16.h>
#include <hip/hip_fp16.h>
#include <math.h>

#define BB 8
#define HH 96
#define WW 96
#define HW 9216
#define BN_EPS 1e-5f

typedef _Float16 f16x2 __attribute__((ext_vector_type(2)));
typedef _Float16 f16x8 __attribute__((ext_vector_type(8)));
typedef float f32x4 __attribute__((ext_vector_type(4)));

union HU  { _Float16 h; unsigned short u; };
union UH2 { unsigned u; f16x2 h; };
union U4H { uint4 u; f16x2 h2[4]; };

// ---- workspace layout (bytes) ----
#define OFF_XT   0
#define SZ_XT    (BB*HW*64*2)          // fp16 x transposed (B,H,W,C)
#define OFF_WB   (OFF_XT + SZ_XT)
#define SZ_WB    (64*576*2)            // wB[o][k*64+c] fp16 (main conv)
#define OFF_WO   (OFF_WB + SZ_WB)
#define SZ_WO    (32*576*2)            // wOff[oc][kk*64+c] fp16 (27 used, rest 0)
#define OFF_BN   (OFF_WO + SZ_WO)
#define SZ_BN    (64*2*4)              // bnS[64], bnB[64]

// ---------------- prep: weight transposes + BN fold ----------------
__global__ __launch_bounds__(256) void prep_kernel(
    const float* __restrict__ weight, const float* __restrict__ offw,
    const float* __restrict__ modw,
    const float* __restrict__ bias, const float* __restrict__ gamma,
    const float* __restrict__ beta, const float* __restrict__ mean,
    const float* __restrict__ var,
    _Float16* __restrict__ wB, _Float16* __restrict__ wOff,
    float* __restrict__ bnS, float* __restrict__ bnB) {
  int tid = blockIdx.x * 256 + threadIdx.x;
  if (tid < 64 * 576) {
    int o = tid / 576, ck = tid % 576;
    int k = ck >> 6, c = ck & 63;                // ck = k*64 + c
    wB[tid] = (_Float16)weight[o * 576 + c * 9 + k];
  }
  int t2 = tid - 64 * 576;
  if (t2 >= 0 && t2 < 32 * 576) {
    int oc = t2 / 576, kcol = t2 % 576;
    int kk = kcol >> 6, c = kcol & 63;           // kcol = kk*64 + c
    float v = 0.f;
    if (oc < 18)      v = offw[(oc * 64 + c) * 9 + kk];
    else if (oc < 27) v = modw[((oc - 18) * 64 + c) * 9 + kk];
    wOff[t2] = (_Float16)v;
  }
  int t3 = tid - (64 * 576 + 32 * 576);
  if (t3 >= 0 && t3 < 64) {
    float inv = gamma[t3] * rsqrtf(var[t3] + BN_EPS);
    bnS[t3] = inv;
    bnB[t3] = (bias[t3] - mean[t3]) * inv + beta[t3];
  }
}

// ---------------- LDS-tiled transpose x -> (B,H,W,C) fp16 (XCD-swizzled) ----
__global__ __launch_bounds__(256) void transpose_x_kernel(
    const float* __restrict__ x, _Float16* __restrict__ xT) {
  __shared__ float tile[64][65];
  int tid = threadIdx.x;
  int b = blockIdx.x & 7;                        // image b stays on one XCD
  int hwb = (blockIdx.x >> 3) * 64;
  int col = tid & 63, g = tid >> 6;
  float r[16];
#pragma unroll
  for (int it = 0; it < 16; ++it)
    r[it] = x[(b * 64 + it * 4 + g) * HW + hwb + col]; // coalesced 256B
  __builtin_amdgcn_sched_barrier(0);
#pragma unroll
  for (int it = 0; it < 16; ++it)
    tile[it * 4 + g][col] = r[it];
  __syncthreads();
#pragma unroll
  for (int it = 0; it < 16; ++it) {
    int p = it * 4 + g;
    xT[(size_t)(b * HW + hwb + p) * 64 + col] = (_Float16)tile[col][p];
  }
}

__device__ __forceinline__ unsigned rep16(float w) {
  HU cv; cv.h = (_Float16)w;
  return 0x10001u * (unsigned)cv.u;
}

// ---------------- FUSED: offset conv + fold + deformable sample + GEMM ----------------
// 32-px row-segment per block (2304 blocks). Phases:
//  0: reg-stage 3x34 neighborhood into padded sN (conv_offsets' proven pattern)
//  1: offset MFMA C[32px][32oc], wave = (mt,nt) quadrant, full-K (verbatim)
//  2: fold 288 recs -> LDS xys/w4s (full-width, 2 passes)
//  3+4: TWO 16-px rounds of r18 sampling + main MFMA GEMM + BN/ReLU epilogue
__global__ __launch_bounds__(256, 6) void dcn_fused_kernel(
    const _Float16* __restrict__ xT, const _Float16* __restrict__ wOff,
    const float* __restrict__ offb, const float* __restrict__ modb,
    const _Float16* __restrict__ wB,
    const float* __restrict__ bnS, const float* __restrict__ bnB,
    float* __restrict__ out) {
  // union region: {sN 14280B + o_off 4224B = 18504B} overlapped by s_A 18688B
  __shared__ __attribute__((aligned(16))) char uLDS[18688];
  __shared__ unsigned xys[288];
  __shared__ __attribute__((aligned(16))) uint4 w4s[288];
  _Float16* sN    = (_Float16*)uLDS;             // [102 pos][70] padded
  float*    o_off = (float*)(uLDS + 14280);      // [32][33]
  _Float16* s_A   = (_Float16*)uLDS;             // [16][584]
  float*    o_lds = (float*)uLDS;                // epilogue alias

  int tid = threadIdx.x;
  int lane = tid & 63;
  int wv = __builtin_amdgcn_readfirstlane(tid >> 6);

  int bi = blockIdx.x;                                 // 8b x 288 tiles (32px)
  int b = bi & 7, rem = bi >> 3;                       // XCD-swizzled: image->XCD
  int h = rem / 3, w0 = (rem % 3) * 32;

  const _Float16* xb = xT + (size_t)b * HW * 64;
  const unsigned char* xbc = (const unsigned char*)xb;

  // ---- phase 0: stage 3 rows x 34 cols x 64 ch (zero-padded OOB) ----
  _Float16 sv[26];
#pragma unroll
  for (int i = 0; i < 26; ++i) {
    int p = wv + 4 * i;
    _Float16 v = (_Float16)0.f;
    if (p < 102) {
      int row = p / 34, col = p - row * 34;
      int y = h + row - 1, xx = w0 + col - 1;
      if ((y >= 0) && (y < HH) && (xx >= 0) && (xx < WW))
        v = xb[(size_t)(y * WW + xx) * 64 + lane];
    }
    sv[i] = v;
  }
  __builtin_amdgcn_sched_barrier(0);
#pragma unroll
  for (int i = 0; i < 26; ++i) {
    int p = wv + 4 * i;
    if (p < 102) sN[p * 70 + lane] = sv[i];
  }
  __syncthreads();

  // ---- phase 1: offset MFMA C[32px][32oc], wave = (mt,nt), full-K ----
  int r = lane & 15, g = lane >> 4;
  {
    int mt = wv >> 1, nt = wv & 1;
    int px = mt * 16 + r;
    const _Float16* bp = wOff + (nt * 16 + r) * 576 + g * 8;
    f32x4 acc = {0.f, 0.f, 0.f, 0.f};
#pragma unroll
    for (int s = 0; s < 18; ++s) {
      int kk = s >> 1, ky = kk / 3, kx = kk - ky * 3;
      f16x8 a  = *(const f16x8*)&sN[(ky * 34 + px + kx) * 70 + (s & 1) * 32 + g * 8];
      f16x8 bb = *(const f16x8*)(bp + s * 32);
      acc = __builtin_amdgcn_mfma_f32_16x16x32_f16(a, bb, acc, 0, 0, 0);
    }
#pragma unroll
    for (int j = 0; j < 4; ++j)
      o_off[(mt * 16 + g * 4 + j) * 33 + nt * 16 + r] = acc[j];
  }
  __syncthreads();

  // ---- phase 2: fold 288 recs -> xys/w4s in LDS ----
  for (int it = tid; it < 288; it += 256) {
    int pxx = it & 31, k = it >> 5;
    int ky = k / 3, kx = k - ky * 3;
    int w = w0 + pxx;

    float offy = o_off[pxx * 33 + 2 * k]     + offb[2 * k];
    float offx = o_off[pxx * 33 + 2 * k + 1] + offb[2 * k + 1];
    float mod  = 2.f / (1.f + __expf(-(o_off[pxx * 33 + 18 + k] + modb[k])));

    float py  = (float)(h - 1 + ky) + offy;
    float px_ = (float)(w - 1 + kx) + offx;
    float y0f = floorf(py), x0f = floorf(px_);
    float dy = py - y0f, dx = px_ - x0f;
    int y0 = (int)y0f, x0 = (int)x0f;
    int y1 = y0 + 1, x1 = x0 + 1;
    bool vy0 = (y0 >= 0) && (y0 < HH), vy1 = (y1 >= 0) && (y1 < HH);
    bool vx0 = (x0 >= 0) && (x0 < WW), vx1 = (x1 >= 0) && (x1 < WW);
    float w00 = (vy0 && vx0) ? (1.f - dy) * (1.f - dx) * mod : 0.f;
    float w01 = (vy0 && vx1) ? (1.f - dy) * dx * mod : 0.f;
    float w10 = (vy1 && vx0) ? dy * (1.f - dx) * mod : 0.f;
    float w11 = (vy1 && vx1) ? dy * dx * mod : 0.f;
    int y0c = min(max(y0, 0), HH - 1), y1c = min(max(y1, 0), HH - 1);
    int x0c = min(max(x0, 0), WW - 1), x1c = min(max(x1, 0), WW - 1);
    int rec = pxx * 9 + k;
    xys[rec] = (unsigned)y0c | ((unsigned)y1c << 8) |
               ((unsigned)x0c << 16) | ((unsigned)x1c << 24);
    w4s[rec] = make_uint4(rep16(w00), rep16(w01), rep16(w10), rep16(w11));
  }
  __syncthreads();

  // ---- phases 3+4: two 16-px rounds (r18 sampling + GEMM, byte-identical) ----
  int hsel = lane >> 5;                                // half index: 0 / 1
  unsigned ch4 = (unsigned)((lane & 31) << 2);         // channel-pair byte off
  int o = wv * 16 + r;                                 // this lane's out channel
  float sc = bnS[o], sh = bnB[o];

  for (int half = 0; half < 2; ++half) {
    int base16 = half * 16;
    int hwrow16 = h * WW + w0 + base16;

#pragma unroll
    for (int px = 0; px < 4; ++px) {
      int pl = wv * 4 + px;
      int mi = (base16 + pl) * 9;
      unsigned q[9];
#pragma unroll
      for (int k = 0; k < 9; ++k) q[k] = xys[mi + k];  // uniform -> broadcast

#pragma unroll
      for (int p4 = 0; p4 < 4; ++p4) {
        const int kA = 2 * p4;
        unsigned qa = q[kA], qb = q[kA + 1];
        unsigned aY0 = qa & 255u, aY1 = (qa >> 8) & 255u;
        unsigned aX0 = (qa >> 16) & 255u, aX1 = qa >> 24;
        unsigned bY0 = qb & 255u, bY1 = (qb >> 8) & 255u;
        unsigned bX0 = (qb >> 16) & 255u, bX1 = qb >> 24;
        unsigned oA0 = (aY0 * WW + aX0) << 7, oA1 = (aY0 * WW + aX1) << 7;
        unsigned oA2 = (aY1 * WW + aX0) << 7, oA3 = (aY1 * WW + aX1) << 7;
        unsigned oB0 = (bY0 * WW + bX0) << 7, oB1 = (bY0 * WW + bX1) << 7;
        unsigned oB2 = (bY1 * WW + bX0) << 7, oB3 = (bY1 * WW + bX1) << 7;
        unsigned a0 = (hsel ? oB0 : oA0) + ch4;
        unsigned a1 = (hsel ? oB1 : oA1) + ch4;
        unsigned a2 = (hsel ? oB2 : oA2) + ch4;
        unsigned a3 = (hsel ? oB3 : oA3) + ch4;
        unsigned t0 = *(const unsigned*)(xbc + a0);
        unsigned t1 = *(const unsigned*)(xbc + a1);
        unsigned t2 = *(const unsigned*)(xbc + a2);
        unsigned t3 = *(const unsigned*)(xbc + a3);
        U4H Wa, Wb;
        Wa.u = w4s[mi + kA]; Wb.u = w4s[mi + kA + 1];  // uniform broadcast
        f16x2 W0 = hsel ? Wb.h2[0] : Wa.h2[0];
        f16x2 W1 = hsel ? Wb.h2[1] : Wa.h2[1];
        f16x2 W2 = hsel ? Wb.h2[2] : Wa.h2[2];
        f16x2 W3 = hsel ? Wb.h2[3] : Wa.h2[3];
        UH2 v0, v1, v2, v3, s;
        v0.u = t0; v1.u = t1; v2.u = t2; v3.u = t3;
        s.h = v0.h * W0 + v1.h * W1 + v2.h * W2 + v3.h * W3;
        *(unsigned*)&s_A[pl * 584 + (kA + hsel) * 64 + (int)(ch4 >> 1)] = s.u;
      }
      { // k = 8: both halves load/compute identically; half0 writes
        unsigned qa = q[8];
        unsigned aY0 = qa & 255u, aY1 = (qa >> 8) & 255u;
        unsigned aX0 = (qa >> 16) & 255u, aX1 = qa >> 24;
        unsigned a0 = (((aY0 * WW + aX0) << 7)) + ch4;
        unsigned a1 = (((aY0 * WW + aX1) << 7)) + ch4;
        unsigned a2 = (((aY1 * WW + aX0) << 7)) + ch4;
        unsigned a3 = (((aY1 * WW + aX1) << 7)) + ch4;
        unsigned t0 = *(const unsigned*)(xbc + a0);
        unsigned t1 = *(const unsigned*)(xbc + a1);
        unsigned t2 = *(const unsigned*)(xbc + a2);
        unsigned t3 = *(const unsigned*)(xbc + a3);
        U4H W; W.u = w4s[mi + 8];
        UH2 v0, v1, v2, v3, s;
        v0.u = t0; v1.u = t1; v2.u = t2; v3.u = t3;
        s.h = v0.h * W.h2[0] + v1.h * W.h2[1] + v2.h * W.h2[2] + v3.h * W.h2[3];
        if (lane < 32)
          *(unsigned*)&s_A[pl * 584 + 512 + (int)(ch4 >> 1)] = s.u;
      }
    }
    __syncthreads();

    // ---- phase 4: [16 x 576] x [576 x 64] fp16 MFMA ----
    const _Float16* arow = s_A + r * 584 + g * 8;
    const _Float16* bp = wB + (wv * 16 + r) * 576 + g * 8;
    f32x4 accA = {0.f, 0.f, 0.f, 0.f}, accB = {0.f, 0.f, 0.f, 0.f};
#pragma unroll 3
    for (int s = 0; s < 18; s += 2) {
      f16x8 a0 = *(const f16x8*)(arow + s * 32);
      f16x8 b0 = *(const f16x8*)(bp + s * 32);
      f16x8 a1 = *(const f16x8*)(arow + s * 32 + 32);
      f16x8 b1 = *(const f16x8*)(bp + s * 32 + 32);
      accA = __builtin_amdgcn_mfma_f32_16x16x32_f16(a0, b0, accA, 0, 0, 0);
      accB = __builtin_amdgcn_mfma_f32_16x16x32_f16(a1, b1, accB, 0, 0, 0);
    }

    // ---- epilogue: fused BN + ReLU, LDS transpose, coalesced store ----
    __syncthreads();                                   // all s_A reads done
#pragma unroll
    for (int j = 0; j < 4; ++j) {
      int px = g * 4 + j;                              // C row = (lane>>4)*4+j
      o_lds[o * 20 + px] = fmaxf((accA[j] + accB[j]) * sc + sh, 0.f);
    }
    __syncthreads();

    int oo = tid >> 2, qd = tid & 3;
    float4 u = *(const float4*)&o_lds[oo * 20 + qd * 4];
    *(float4*)(out + (size_t)(b * 64 + oo) * HW + hwrow16 + qd * 4) = u;
    __syncthreads();                                   // before next half reuse
  }
}

extern "C" void kernel_launch(void* const* d_in, const int* in_sizes, int n_in,
                              void* d_out, int out_size, void* d_ws, size_t ws_size,
                              hipStream_t stream) {
  const float* x      = (const float*)d_in[0];
  const float* offw   = (const float*)d_in[1];
  const float* offb   = (const float*)d_in[2];
  const float* modw   = (const float*)d_in[3];
  const float* modb   = (const float*)d_in[4];
  const float* weight = (const float*)d_in[5];
  const float* bias   = (const float*)d_in[6];
  const float* gamma  = (const float*)d_in[7];
  const float* beta   = (const float*)d_in[8];
  const float* mean   = (const float*)d_in[9];
  const float* var    = (const float*)d_in[10];

  char* ws = (char*)d_ws;
  _Float16*  xTh   = (_Float16*)(ws + OFF_XT);
  _Float16*  wB    = (_Float16*)(ws + OFF_WB);
  _Float16*  wOff  = (_Float16*)(ws + OFF_WO);
  float*     bnS   = (float*)(ws + OFF_BN);
  float*     bnB   = bnS + 64;

  prep_kernel<<<217, 256, 0, stream>>>(weight, offw, modw, bias, gamma, beta,
                                       mean, var, wB, wOff, bnS, bnB);
  transpose_x_kernel<<<1152, 256, 0, stream>>>(x, xTh);
  dcn_fused_kernel<<<2304, 256, 0, stream>>>(xTh, wOff, offb, modb, wB,
                                             bnS, bnB, (float*)d_out);
}

// Round 20
// 89.742 us; speedup vs baseline: 1.0443x; 1.0443x over previous
//
#include <hip/hip_runtime.h>
#include <hip/hip_bf16.h>
#include <hip/hip_fp16.h>
#include <math.h>

#define BB 8
#define HH 96
#define WW 96
#define HW 9216
#define BN_EPS 1e-5f

typedef _Float16 f16x2 __attribute__((ext_vector_type(2)));
typedef _Float16 f16x8 __attribute__((ext_vector_type(8)));
typedef float f32x4 __attribute__((ext_vector_type(4)));

union HU  { _Float16 h; unsigned short u; };
union UH2 { unsigned u; f16x2 h; };
union U4H { uint4 u; f16x2 h2[4]; };

// ---- workspace layout (bytes) ----
#define OFF_XT   0
#define SZ_XT    (BB*HW*64*2)          // fp16 x transposed (B,H,W,C)
#define OFF_WB   (OFF_XT + SZ_XT)
#define SZ_WB    (64*576*2)            // wB[o][k*64+c] fp16 (main conv)
#define OFF_WO   (OFF_WB + SZ_WB)
#define SZ_WO    (32*576*2)            // wOff[oc][kk*64+c] fp16 (27 used, rest 0)
#define OFF_BN   (OFF_WO + SZ_WO)
#define SZ_BN    (64*2*4)              // bnS[64], bnB[64]

// ---------------- prep: weight transposes + BN fold ----------------
__global__ __launch_bounds__(256) void prep_kernel(
    const float* __restrict__ weight, const float* __restrict__ offw,
    const float* __restrict__ modw,
    const float* __restrict__ bias, const float* __restrict__ gamma,
    const float* __restrict__ beta, const float* __restrict__ mean,
    const float* __restrict__ var,
    _Float16* __restrict__ wB, _Float16* __restrict__ wOff,
    float* __restrict__ bnS, float* __restrict__ bnB) {
  int tid = blockIdx.x * 256 + threadIdx.x;
  if (tid < 64 * 576) {
    int o = tid / 576, ck = tid % 576;
    int k = ck >> 6, c = ck & 63;                // ck = k*64 + c
    wB[tid] = (_Float16)weight[o * 576 + c * 9 + k];
  }
  int t2 = tid - 64 * 576;
  if (t2 >= 0 && t2 < 32 * 576) {
    int oc = t2 / 576, kcol = t2 % 576;
    int kk = kcol >> 6, c = kcol & 63;           // kcol = kk*64 + c
    float v = 0.f;
    if (oc < 18)      v = offw[(oc * 64 + c) * 9 + kk];
    else if (oc < 27) v = modw[((oc - 18) * 64 + c) * 9 + kk];
    wOff[t2] = (_Float16)v;
  }
  int t3 = tid - (64 * 576 + 32 * 576);
  if (t3 >= 0 && t3 < 64) {
    float inv = gamma[t3] * rsqrtf(var[t3] + BN_EPS);
    bnS[t3] = inv;
    bnB[t3] = (bias[t3] - mean[t3]) * inv + beta[t3];
  }
}

// ---------------- LDS-tiled transpose x -> (B,H,W,C) fp16 (XCD-swizzled) ----
__global__ __launch_bounds__(256) void transpose_x_kernel(
    const float* __restrict__ x, _Float16* __restrict__ xT) {
  __shared__ float tile[64][65];
  int tid = threadIdx.x;
  int b = blockIdx.x & 7;                        // image b stays on one XCD
  int hwb = (blockIdx.x >> 3) * 64;
  int col = tid & 63, g = tid >> 6;
  float r[16];
#pragma unroll
  for (int it = 0; it < 16; ++it)
    r[it] = x[(b * 64 + it * 4 + g) * HW + hwb + col]; // coalesced 256B
  __builtin_amdgcn_sched_barrier(0);
#pragma unroll
  for (int it = 0; it < 16; ++it)
    tile[it * 4 + g][col] = r[it];
  __syncthreads();
#pragma unroll
  for (int it = 0; it < 16; ++it) {
    int p = it * 4 + g;
    xT[(size_t)(b * HW + hwb + p) * 64 + col] = (_Float16)tile[col][p];
  }
}

__device__ __forceinline__ unsigned rep16(float w) {
  HU cv; cv.h = (_Float16)w;
  return 0x10001u * (unsigned)cv.u;
}

// ---------------- FUSED: offset conv + fold + deformable sample + GEMM ----------------
// One 16-px row-segment per block. Phases:
//  0: reg-stage 3x18 neighborhood into padded sN (proven conv_offsets pattern)
//  1: offset GEMM A[16][576] x wOff[576][32]: 4 waves = 2 oc-tiles x 2 K-halves
//  2: fold (144 recs): sigmoid + bilinear + taps -> LDS xys/w4s (no global meta)
//  3: r12 sampling verbatim, meta from LDS broadcast instead of s_loads
//  4: r12 phase-B MFMA GEMM + BN/ReLU epilogue (byte-identical)
__global__ __launch_bounds__(256, 6) void dcn_fused_kernel(
    const _Float16* __restrict__ xT, const _Float16* __restrict__ wOff,
    const float* __restrict__ offb, const float* __restrict__ modb,
    const _Float16* __restrict__ wB,
    const float* __restrict__ bnS, const float* __restrict__ bnB,
    float* __restrict__ out) {
  // union region: {sN 7776B, o_part 4224B} overlapped by s_A 18688B (o_lds)
  __shared__ __attribute__((aligned(16))) char uLDS[18688];
  __shared__ unsigned xys[144];
  __shared__ __attribute__((aligned(16))) uint4 w4s[144];
  _Float16* sN     = (_Float16*)uLDS;            // [54 pos][72] padded
  float*    o_part = (float*)(uLDS + 7776);      // [2][16*33]
  _Float16* s_A    = (_Float16*)uLDS;            // [16][584]
  float*    o_lds  = (float*)uLDS;               // epilogue alias

  int tid = threadIdx.x;
  int lane = tid & 63;
  int wv = __builtin_amdgcn_readfirstlane(tid >> 6);

  int bi = blockIdx.x;                                 // 8b x 576 tiles
  int b = bi & 7, t = bi >> 3;                         // XCD-swizzled: image->XCD
  int h = t / 6, w0 = (t - (t / 6) * 6) * 16;
  int hwrow = h * WW + w0;

  const _Float16* xb = xT + (size_t)b * HW * 64;
  const unsigned char* xbc = (const unsigned char*)xb;

  // ---- phase 0: stage 3 rows x 18 cols x 64 ch (zero-padded OOB) ----
  _Float16 sv[14];
#pragma unroll
  for (int i = 0; i < 14; ++i) {
    int p = wv + 4 * i;
    _Float16 v = (_Float16)0.f;
    if (p < 54) {
      int row = p / 18, col = p - row * 18;
      int y = h + row - 1, xx = w0 + col - 1;
      if ((y >= 0) && (y < HH) && (xx >= 0) && (xx < WW))
        v = xb[(size_t)(y * WW + xx) * 64 + lane];
    }
    sv[i] = v;
  }
  __builtin_amdgcn_sched_barrier(0);
#pragma unroll
  for (int i = 0; i < 14; ++i) {
    int p = wv + 4 * i;
    if (p < 54) sN[p * 72 + lane] = sv[i];
  }
  __syncthreads();

  // ---- phase 1: offset MFMA, wave = (K-half ks, oc-tile nt) ----
  int r = lane & 15, g = lane >> 4;
  {
    int nt = wv & 1, ks = wv >> 1;
    const _Float16* bp = wOff + (nt * 16 + r) * 576 + ks * 288 + g * 8;
    f32x4 acc = {0.f, 0.f, 0.f, 0.f};
#pragma unroll
    for (int si = 0; si < 9; ++si) {
      int s = ks * 9 + si;
      int kk = s >> 1, ky = kk / 3, kx = kk - ky * 3, ch = s & 1;
      f16x8 a  = *(const f16x8*)&sN[(ky * 18 + r + kx) * 72 + ch * 32 + g * 8];
      f16x8 bb = *(const f16x8*)(bp + si * 32);
      acc = __builtin_amdgcn_mfma_f32_16x16x32_f16(a, bb, acc, 0, 0, 0);
    }
#pragma unroll
    for (int j = 0; j < 4; ++j)
      o_part[ks * 528 + (g * 4 + j) * 33 + nt * 16 + r] = acc[j];
  }
  __syncthreads();

  // ---- phase 2: fold -> xys/w4s in LDS ----
  if (tid < 144) {
    int px = tid / 9, k = tid - px * 9;
    int ky = k / 3, kx = k - ky * 3;
    int w = w0 + px;
    float offy = o_part[px * 33 + 2 * k]     + o_part[528 + px * 33 + 2 * k]     + offb[2 * k];
    float offx = o_part[px * 33 + 2 * k + 1] + o_part[528 + px * 33 + 2 * k + 1] + offb[2 * k + 1];
    float mz   = o_part[px * 33 + 18 + k]    + o_part[528 + px * 33 + 18 + k]    + modb[k];
    float mod  = 2.f / (1.f + __expf(-mz));

    float py  = (float)(h - 1 + ky) + offy;
    float px_ = (float)(w - 1 + kx) + offx;
    float y0f = floorf(py), x0f = floorf(px_);
    float dy = py - y0f, dx = px_ - x0f;
    int y0 = (int)y0f, x0 = (int)x0f;
    int y1 = y0 + 1, x1 = x0 + 1;
    bool vy0 = (y0 >= 0) && (y0 < HH), vy1 = (y1 >= 0) && (y1 < HH);
    bool vx0 = (x0 >= 0) && (x0 < WW), vx1 = (x1 >= 0) && (x1 < WW);
    float w00 = (vy0 && vx0) ? (1.f - dy) * (1.f - dx) * mod : 0.f;
    float w01 = (vy0 && vx1) ? (1.f - dy) * dx * mod : 0.f;
    float w10 = (vy1 && vx0) ? dy * (1.f - dx) * mod : 0.f;
    float w11 = (vy1 && vx1) ? dy * dx * mod : 0.f;
    int y0c = min(max(y0, 0), HH - 1), y1c = min(max(y1, 0), HH - 1);
    int x0c = min(max(x0, 0), WW - 1), x1c = min(max(x1, 0), WW - 1);
    xys[tid] = (unsigned)y0c | ((unsigned)y1c << 8) |
               ((unsigned)x0c << 16) | ((unsigned)x1c << 24);
    w4s[tid] = make_uint4(rep16(w00), rep16(w01), rep16(w10), rep16(w11));
  }
  __syncthreads();

  // ---- phase 3: r12 sampling, meta from LDS ----
  int hsel = lane >> 5;                                // half index: 0 / 1
  unsigned ch4 = (unsigned)((lane & 31) << 2);         // channel-pair byte off

#pragma unroll
  for (int px = 0; px < 4; ++px) {
    int pl = wv * 4 + px;
    int mi = pl * 9;
    unsigned q[9];
#pragma unroll
    for (int k = 0; k < 9; ++k) q[k] = xys[mi + k];    // uniform -> broadcast

#pragma unroll
    for (int p4 = 0; p4 < 4; ++p4) {
      const int kA = 2 * p4;
      unsigned qa = q[kA], qb = q[kA + 1];
      unsigned aY0 = qa & 255u, aY1 = (qa >> 8) & 255u;
      unsigned aX0 = (qa >> 16) & 255u, aX1 = qa >> 24;
      unsigned bY0 = qb & 255u, bY1 = (qb >> 8) & 255u;
      unsigned bX0 = (qb >> 16) & 255u, bX1 = qb >> 24;
      unsigned oA0 = (aY0 * WW + aX0) << 7, oA1 = (aY0 * WW + aX1) << 7;
      unsigned oA2 = (aY1 * WW + aX0) << 7, oA3 = (aY1 * WW + aX1) << 7;
      unsigned oB0 = (bY0 * WW + bX0) << 7, oB1 = (bY0 * WW + bX1) << 7;
      unsigned oB2 = (bY1 * WW + bX0) << 7, oB3 = (bY1 * WW + bX1) << 7;
      unsigned a0 = (hsel ? oB0 : oA0) + ch4;
      unsigned a1 = (hsel ? oB1 : oA1) + ch4;
      unsigned a2 = (hsel ? oB2 : oA2) + ch4;
      unsigned a3 = (hsel ? oB3 : oA3) + ch4;
      unsigned t0 = *(const unsigned*)(xbc + a0);
      unsigned t1 = *(const unsigned*)(xbc + a1);
      unsigned t2 = *(const unsigned*)(xbc + a2);
      unsigned t3 = *(const unsigned*)(xbc + a3);
      U4H Wa, Wb;
      Wa.u = w4s[mi + kA]; Wb.u = w4s[mi + kA + 1];    // uniform broadcast
      f16x2 W0 = hsel ? Wb.h2[0] : Wa.h2[0];
      f16x2 W1 = hsel ? Wb.h2[1] : Wa.h2[1];
      f16x2 W2 = hsel ? Wb.h2[2] : Wa.h2[2];
      f16x2 W3 = hsel ? Wb.h2[3] : Wa.h2[3];
      UH2 v0, v1, v2, v3, s;
      v0.u = t0; v1.u = t1; v2.u = t2; v3.u = t3;
      s.h = v0.h * W0 + v1.h * W1 + v2.h * W2 + v3.h * W3;
      *(unsigned*)&s_A[pl * 584 + (kA + hsel) * 64 + (int)(ch4 >> 1)] = s.u;
    }
    { // k = 8: both halves load/compute identically; half0 writes
      unsigned qa = q[8];
      unsigned aY0 = qa & 255u, aY1 = (qa >> 8) & 255u;
      unsigned aX0 = (qa >> 16) & 255u, aX1 = qa >> 24;
      unsigned a0 = (((aY0 * WW + aX0) << 7)) + ch4;
      unsigned a1 = (((aY0 * WW + aX1) << 7)) + ch4;
      unsigned a2 = (((aY1 * WW + aX0) << 7)) + ch4;
      unsigned a3 = (((aY1 * WW + aX1) << 7)) + ch4;
      unsigned t0 = *(const unsigned*)(xbc + a0);
      unsigned t1 = *(const unsigned*)(xbc + a1);
      unsigned t2 = *(const unsigned*)(xbc + a2);
      unsigned t3 = *(const unsigned*)(xbc + a3);
      U4H W; W.u = w4s[mi + 8];
      UH2 v0, v1, v2, v3, s;
      v0.u = t0; v1.u = t1; v2.u = t2; v3.u = t3;
      s.h = v0.h * W.h2[0] + v1.h * W.h2[1] + v2.h * W.h2[2] + v3.h * W.h2[3];
      if (lane < 32)
        *(unsigned*)&s_A[pl * 584 + 512 + (int)(ch4 >> 1)] = s.u;
    }
  }
  __syncthreads();

  // ---- phase 4: [16 x 576] x [576 x 64] fp16 MFMA, wave -> 16 out-channels ----
  const _Float16* arow = s_A + r * 584 + g * 8;
  const _Float16* bp = wB + (wv * 16 + r) * 576 + g * 8;
  f32x4 accA = {0.f, 0.f, 0.f, 0.f}, accB = {0.f, 0.f, 0.f, 0.f};
#pragma unroll 3
  for (int s = 0; s < 18; s += 2) {
    f16x8 a0 = *(const f16x8*)(arow + s * 32);
    f16x8 b0 = *(const f16x8*)(bp + s * 32);
    f16x8 a1 = *(const f16x8*)(arow + s * 32 + 32);
    f16x8 b1 = *(const f16x8*)(bp + s * 32 + 32);
    accA = __builtin_amdgcn_mfma_f32_16x16x32_f16(a0, b0, accA, 0, 0, 0);
    accB = __builtin_amdgcn_mfma_f32_16x16x32_f16(a1, b1, accB, 0, 0, 0);
  }

  // ---- epilogue: fused BN + ReLU, LDS transpose, coalesced store ----
  int o = wv * 16 + r;                                 // this lane's out channel
  float sc = bnS[o], sh = bnB[o];
  __syncthreads();                                     // all s_A reads done
#pragma unroll
  for (int j = 0; j < 4; ++j) {
    int px = g * 4 + j;                                // C row = (lane>>4)*4+j
    o_lds[o * 20 + px] = fmaxf((accA[j] + accB[j]) * sc + sh, 0.f);
  }
  __syncthreads();

  int oo = tid >> 2, qd = tid & 3;
  float4 u = *(const float4*)&o_lds[oo * 20 + qd * 4];
  *(float4*)(out + (size_t)(b * 64 + oo) * HW + hwrow + qd * 4) = u;
}

extern "C" void kernel_launch(void* const* d_in, const int* in_sizes, int n_in,
                              void* d_out, int out_size, void* d_ws, size_t ws_size,
                              hipStream_t stream) {
  const float* x      = (const float*)d_in[0];
  const float* offw   = (const float*)d_in[1];
  const float* offb   = (const float*)d_in[2];
  const float* modw   = (const float*)d_in[3];
  const float* modb   = (const float*)d_in[4];
  const float* weight = (const float*)d_in[5];
  const float* bias   = (const float*)d_in[6];
  const float* gamma  = (const float*)d_in[7];
  const float* beta   = (const float*)d_in[8];
  const float* mean   = (const float*)d_in[9];
  const float* var    = (const float*)d_in[10];

  char* ws = (char*)d_ws;
  _Float16*  xTh   = (_Float16*)(ws + OFF_XT);
  _Float16*  wB    = (_Float16*)(ws + OFF_WB);
  _Float16*  wOff  = (_Float16*)(ws + OFF_WO);
  float*     bnS   = (float*)(ws + OFF_BN);
  float*     bnB   = bnS + 64;

  prep_kernel<<<217, 256, 0, stream>>>(weight, offw, modw, bias, gamma, beta,
                                       mean, var, wB, wOff, bnS, bnB);
  transpose_x_kernel<<<1152, 256, 0, stream>>>(x, xTh);
  dcn_fused_kernel<<<4608, 256, 0, stream>>>(xTh, wOff, offb, modb, wB,
                                             bnS, bnB, (float*)d_out);
}

// Round 21
// 89.236 us; speedup vs baseline: 1.0502x; 1.0057x over previous
//
#include <hip/hip_runtime.h>
#include <hip/hip_bf16.h>
#include <hip/hip_fp16.h>
#include <math.h>

#define BB 8
#define HH 96
#define WW 96
#define HW 9216
#define BN_EPS 1e-5f

typedef _Float16 f16x2 __attribute__((ext_vector_type(2)));
typedef _Float16 f16x8 __attribute__((ext_vector_type(8)));
typedef float f32x4 __attribute__((ext_vector_type(4)));

union HU  { _Float16 h; unsigned short u; };
union UH2 { unsigned u; f16x2 h; };

// ---- workspace layout (bytes) ----
#define OFF_XT   0
#define SZ_XT    (BB*HW*64*2)          // fp16 x transposed (B,H,W,C)
#define OFF_WB   (OFF_XT + SZ_XT)
#define SZ_WB    (64*576*2)            // wB[o][k*64+c] fp16 (main conv)
#define OFF_WO   (OFF_WB + SZ_WB)
#define SZ_WO    (32*576*2)            // wOff[oc][kk*64+c] fp16 (27 used, rest 0)
#define OFF_BN   (OFF_WO + SZ_WO)
#define SZ_BN    (64*2*4)              // bnS[64], bnB[64]

// ---------------- prep: weight transposes + BN fold ----------------
__global__ __launch_bounds__(256) void prep_kernel(
    const float* __restrict__ weight, const float* __restrict__ offw,
    const float* __restrict__ modw,
    const float* __restrict__ bias, const float* __restrict__ gamma,
    const float* __restrict__ beta, const float* __restrict__ mean,
    const float* __restrict__ var,
    _Float16* __restrict__ wB, _Float16* __restrict__ wOff,
    float* __restrict__ bnS, float* __restrict__ bnB) {
  int tid = blockIdx.x * 256 + threadIdx.x;
  if (tid < 64 * 576) {
    int o = tid / 576, ck = tid % 576;
    int k = ck >> 6, c = ck & 63;                // ck = k*64 + c
    wB[tid] = (_Float16)weight[o * 576 + c * 9 + k];
  }
  int t2 = tid - 64 * 576;
  if (t2 >= 0 && t2 < 32 * 576) {
    int oc = t2 / 576, kcol = t2 % 576;
    int kk = kcol >> 6, c = kcol & 63;           // kcol = kk*64 + c
    float v = 0.f;
    if (oc < 18)      v = offw[(oc * 64 + c) * 9 + kk];
    else if (oc < 27) v = modw[((oc - 18) * 64 + c) * 9 + kk];
    wOff[t2] = (_Float16)v;
  }
  int t3 = tid - (64 * 576 + 32 * 576);
  if (t3 >= 0 && t3 < 64) {
    float inv = gamma[t3] * rsqrtf(var[t3] + BN_EPS);
    bnS[t3] = inv;
    bnB[t3] = (bias[t3] - mean[t3]) * inv + beta[t3];
  }
}

// ---------------- LDS-tiled transpose x -> (B,H,W,C) fp16 (XCD-swizzled) ----
__global__ __launch_bounds__(256) void transpose_x_kernel(
    const float* __restrict__ x, _Float16* __restrict__ xT) {
  __shared__ float tile[64][65];
  int tid = threadIdx.x;
  int b = blockIdx.x & 7;                        // image b stays on one XCD
  int hwb = (blockIdx.x >> 3) * 64;
  int col = tid & 63, g = tid >> 6;
  float r[16];
#pragma unroll
  for (int it = 0; it < 16; ++it)
    r[it] = x[(b * 64 + it * 4 + g) * HW + hwb + col]; // coalesced 256B
  __builtin_amdgcn_sched_barrier(0);
#pragma unroll
  for (int it = 0; it < 16; ++it)
    tile[it * 4 + g][col] = r[it];
  __syncthreads();
#pragma unroll
  for (int it = 0; it < 16; ++it) {
    int p = it * 4 + g;
    xT[(size_t)(b * HW + hwb + p) * 64 + col] = (_Float16)tile[col][p];
  }
}

// ---------------- FUSED: offset conv + fold + deformable sample + GEMM ----------------
// r18 structure with occupancy unlock: w4s stored UNREPLICATED (uint2, 8B/rec)
// and replicated in-register at use -> LDS 22016 -> 20416B -> 8 blocks/CU.
__global__ __launch_bounds__(256, 8) void dcn_fused_kernel(
    const _Float16* __restrict__ xT, const _Float16* __restrict__ wOff,
    const float* __restrict__ offb, const float* __restrict__ modb,
    const _Float16* __restrict__ wB,
    const float* __restrict__ bnS, const float* __restrict__ bnB,
    float* __restrict__ out) {
  // union region: {sN 7776B, o_part 4224B} overlapped by s_A 18688B (o_lds)
  __shared__ __attribute__((aligned(16))) char uLDS[18688];
  __shared__ unsigned xys[144];
  __shared__ __attribute__((aligned(8))) uint2 w4s[144];   // packed f16 quads
  _Float16* sN     = (_Float16*)uLDS;            // [54 pos][72] padded
  float*    o_part = (float*)(uLDS + 7776);      // [2][16*33]
  _Float16* s_A    = (_Float16*)uLDS;            // [16][584]
  float*    o_lds  = (float*)uLDS;               // epilogue alias

  int tid = threadIdx.x;
  int lane = tid & 63;
  int wv = __builtin_amdgcn_readfirstlane(tid >> 6);

  int bi = blockIdx.x;                                 // 8b x 576 tiles
  int b = bi & 7, t = bi >> 3;                         // XCD-swizzled: image->XCD
  int h = t / 6, w0 = (t - (t / 6) * 6) * 16;
  int hwrow = h * WW + w0;

  const _Float16* xb = xT + (size_t)b * HW * 64;
  const unsigned char* xbc = (const unsigned char*)xb;

  // ---- phase 0: stage 3 rows x 18 cols x 64 ch (zero-padded OOB) ----
  _Float16 sv[14];
#pragma unroll
  for (int i = 0; i < 14; ++i) {
    int p = wv + 4 * i;
    _Float16 v = (_Float16)0.f;
    if (p < 54) {
      int row = p / 18, col = p - row * 18;
      int y = h + row - 1, xx = w0 + col - 1;
      if ((y >= 0) && (y < HH) && (xx >= 0) && (xx < WW))
        v = xb[(size_t)(y * WW + xx) * 64 + lane];
    }
    sv[i] = v;
  }
  __builtin_amdgcn_sched_barrier(0);
#pragma unroll
  for (int i = 0; i < 14; ++i) {
    int p = wv + 4 * i;
    if (p < 54) sN[p * 72 + lane] = sv[i];
  }
  __syncthreads();

  // ---- phase 1: offset MFMA, wave = (K-half ks, oc-tile nt) ----
  int r = lane & 15, g = lane >> 4;
  {
    int nt = wv & 1, ks = wv >> 1;
    const _Float16* bp = wOff + (nt * 16 + r) * 576 + ks * 288 + g * 8;
    f32x4 acc = {0.f, 0.f, 0.f, 0.f};
#pragma unroll
    for (int si = 0; si < 9; ++si) {
      int s = ks * 9 + si;
      int kk = s >> 1, ky = kk / 3, kx = kk - ky * 3, ch = s & 1;
      f16x8 a  = *(const f16x8*)&sN[(ky * 18 + r + kx) * 72 + ch * 32 + g * 8];
      f16x8 bb = *(const f16x8*)(bp + si * 32);
      acc = __builtin_amdgcn_mfma_f32_16x16x32_f16(a, bb, acc, 0, 0, 0);
    }
#pragma unroll
    for (int j = 0; j < 4; ++j)
      o_part[ks * 528 + (g * 4 + j) * 33 + nt * 16 + r] = acc[j];
  }
  __syncthreads();

  // ---- phase 2: fold -> xys/w4s (packed) in LDS ----
  if (tid < 144) {
    int px = tid / 9, k = tid - px * 9;
    int ky = k / 3, kx = k - ky * 3;
    int w = w0 + px;
    float offy = o_part[px * 33 + 2 * k]     + o_part[528 + px * 33 + 2 * k]     + offb[2 * k];
    float offx = o_part[px * 33 + 2 * k + 1] + o_part[528 + px * 33 + 2 * k + 1] + offb[2 * k + 1];
    float mz   = o_part[px * 33 + 18 + k]    + o_part[528 + px * 33 + 18 + k]    + modb[k];
    float mod  = 2.f / (1.f + __expf(-mz));

    float py  = (float)(h - 1 + ky) + offy;
    float px_ = (float)(w - 1 + kx) + offx;
    float y0f = floorf(py), x0f = floorf(px_);
    float dy = py - y0f, dx = px_ - x0f;
    int y0 = (int)y0f, x0 = (int)x0f;
    int y1 = y0 + 1, x1 = x0 + 1;
    bool vy0 = (y0 >= 0) && (y0 < HH), vy1 = (y1 >= 0) && (y1 < HH);
    bool vx0 = (x0 >= 0) && (x0 < WW), vx1 = (x1 >= 0) && (x1 < WW);
    float w00 = (vy0 && vx0) ? (1.f - dy) * (1.f - dx) * mod : 0.f;
    float w01 = (vy0 && vx1) ? (1.f - dy) * dx * mod : 0.f;
    float w10 = (vy1 && vx0) ? dy * (1.f - dx) * mod : 0.f;
    float w11 = (vy1 && vx1) ? dy * dx * mod : 0.f;
    int y0c = min(max(y0, 0), HH - 1), y1c = min(max(y1, 0), HH - 1);
    int x0c = min(max(x0, 0), WW - 1), x1c = min(max(x1, 0), WW - 1);
    xys[tid] = (unsigned)y0c | ((unsigned)y1c << 8) |
               ((unsigned)x0c << 16) | ((unsigned)x1c << 24);
    HU h00, h01, h10, h11;
    h00.h = (_Float16)w00; h01.h = (_Float16)w01;
    h10.h = (_Float16)w10; h11.h = (_Float16)w11;
    w4s[tid] = make_uint2(((unsigned)h01.u << 16) | h00.u,
                          ((unsigned)h11.u << 16) | h10.u);
  }
  __syncthreads();

  // ---- phase 3: r18 sampling, meta from LDS (weights replicated in-register) ----
  int hsel = lane >> 5;                                // half index: 0 / 1
  unsigned ch4 = (unsigned)((lane & 31) << 2);         // channel-pair byte off

#pragma unroll
  for (int px = 0; px < 4; ++px) {
    int pl = wv * 4 + px;
    int mi = pl * 9;
    unsigned q[9];
#pragma unroll
    for (int k = 0; k < 9; ++k) q[k] = xys[mi + k];    // uniform -> broadcast

#pragma unroll
    for (int p4 = 0; p4 < 4; ++p4) {
      const int kA = 2 * p4;
      unsigned qa = q[kA], qb = q[kA + 1];
      unsigned aY0 = qa & 255u, aY1 = (qa >> 8) & 255u;
      unsigned aX0 = (qa >> 16) & 255u, aX1 = qa >> 24;
      unsigned bY0 = qb & 255u, bY1 = (qb >> 8) & 255u;
      unsigned bX0 = (qb >> 16) & 255u, bX1 = qb >> 24;
      unsigned oA0 = (aY0 * WW + aX0) << 7, oA1 = (aY0 * WW + aX1) << 7;
      unsigned oA2 = (aY1 * WW + aX0) << 7, oA3 = (aY1 * WW + aX1) << 7;
      unsigned oB0 = (bY0 * WW + bX0) << 7, oB1 = (bY0 * WW + bX1) << 7;
      unsigned oB2 = (bY1 * WW + bX0) << 7, oB3 = (bY1 * WW + bX1) << 7;
      unsigned a0 = (hsel ? oB0 : oA0) + ch4;
      unsigned a1 = (hsel ? oB1 : oA1) + ch4;
      unsigned a2 = (hsel ? oB2 : oA2) + ch4;
      unsigned a3 = (hsel ? oB3 : oA3) + ch4;
      unsigned t0 = *(const unsigned*)(xbc + a0);
      unsigned t1 = *(const unsigned*)(xbc + a1);
      unsigned t2 = *(const unsigned*)(xbc + a2);
      unsigned t3 = *(const unsigned*)(xbc + a3);
      uint2 Wa = w4s[mi + kA], Wb = w4s[mi + kA + 1];  // uniform broadcast
      unsigned wx = hsel ? Wb.x : Wa.x;
      unsigned wy = hsel ? Wb.y : Wa.y;
      UH2 W0, W1, W2, W3;
      W0.u = (wx << 16) | (wx & 0xffffu);              // (w00,w00)
      W1.u = (wx & 0xffff0000u) | (wx >> 16);          // (w01,w01)
      W2.u = (wy << 16) | (wy & 0xffffu);              // (w10,w10)
      W3.u = (wy & 0xffff0000u) | (wy >> 16);          // (w11,w11)
      UH2 v0, v1, v2, v3, s;
      v0.u = t0; v1.u = t1; v2.u = t2; v3.u = t3;
      s.h = v0.h * W0.h + v1.h * W1.h + v2.h * W2.h + v3.h * W3.h;
      *(unsigned*)&s_A[pl * 584 + (kA + hsel) * 64 + (int)(ch4 >> 1)] = s.u;
    }
    { // k = 8: both halves load/compute identically; half0 writes
      unsigned qa = q[8];
      unsigned aY0 = qa & 255u, aY1 = (qa >> 8) & 255u;
      unsigned aX0 = (qa >> 16) & 255u, aX1 = qa >> 24;
      unsigned a0 = (((aY0 * WW + aX0) << 7)) + ch4;
      unsigned a1 = (((aY0 * WW + aX1) << 7)) + ch4;
      unsigned a2 = (((aY1 * WW + aX0) << 7)) + ch4;
      unsigned a3 = (((aY1 * WW + aX1) << 7)) + ch4;
      unsigned t0 = *(const unsigned*)(xbc + a0);
      unsigned t1 = *(const unsigned*)(xbc + a1);
      unsigned t2 = *(const unsigned*)(xbc + a2);
      unsigned t3 = *(const unsigned*)(xbc + a3);
      uint2 Wp = w4s[mi + 8];
      UH2 W0, W1, W2, W3;
      W0.u = (Wp.x << 16) | (Wp.x & 0xffffu);
      W1.u = (Wp.x & 0xffff0000u) | (Wp.x >> 16);
      W2.u = (Wp.y << 16) | (Wp.y & 0xffffu);
      W3.u = (Wp.y & 0xffff0000u) | (Wp.y >> 16);
      UH2 v0, v1, v2, v3, s;
      v0.u = t0; v1.u = t1; v2.u = t2; v3.u = t3;
      s.h = v0.h * W0.h + v1.h * W1.h + v2.h * W2.h + v3.h * W3.h;
      if (lane < 32)
        *(unsigned*)&s_A[pl * 584 + 512 + (int)(ch4 >> 1)] = s.u;
    }
  }
  __syncthreads();

  // ---- phase 4: [16 x 576] x [576 x 64] fp16 MFMA, wave -> 16 out-channels ----
  const _Float16* arow = s_A + r * 584 + g * 8;
  const _Float16* bp = wB + (wv * 16 + r) * 576 + g * 8;
  f32x4 accA = {0.f, 0.f, 0.f, 0.f}, accB = {0.f, 0.f, 0.f, 0.f};
#pragma unroll 3
  for (int s = 0; s < 18; s += 2) {
    f16x8 a0 = *(const f16x8*)(arow + s * 32);
    f16x8 b0 = *(const f16x8*)(bp + s * 32);
    f16x8 a1 = *(const f16x8*)(arow + s * 32 + 32);
    f16x8 b1 = *(const f16x8*)(bp + s * 32 + 32);
    accA = __builtin_amdgcn_mfma_f32_16x16x32_f16(a0, b0, accA, 0, 0, 0);
    accB = __builtin_amdgcn_mfma_f32_16x16x32_f16(a1, b1, accB, 0, 0, 0);
  }

  // ---- epilogue: fused BN + ReLU, LDS transpose, coalesced store ----
  int o = wv * 16 + r;                                 // this lane's out channel
  float sc = bnS[o], sh = bnB[o];
  __syncthreads();                                     // all s_A reads done
#pragma unroll
  for (int j = 0; j < 4; ++j) {
    int px = g * 4 + j;                                // C row = (lane>>4)*4+j
    o_lds[o * 20 + px] = fmaxf((accA[j] + accB[j]) * sc + sh, 0.f);
  }
  __syncthreads();

  int oo = tid >> 2, qd = tid & 3;
  float4 u = *(const float4*)&o_lds[oo * 20 + qd * 4];
  *(float4*)(out + (size_t)(b * 64 + oo) * HW + hwrow + qd * 4) = u;
}

extern "C" void kernel_launch(void* const* d_in, const int* in_sizes, int n_in,
                              void* d_out, int out_size, void* d_ws, size_t ws_size,
                              hipStream_t stream) {
  const float* x      = (const float*)d_in[0];
  const float* offw   = (const float*)d_in[1];
  const float* offb   = (const float*)d_in[2];
  const float* modw   = (const float*)d_in[3];
  const float* modb   = (const float*)d_in[4];
  const float* weight = (const float*)d_in[5];
  const float* bias   = (const float*)d_in[6];
  const float* gamma  = (const float*)d_in[7];
  const float* beta   = (const float*)d_in[8];
  const float* mean   = (const float*)d_in[9];
  const float* var    = (const float*)d_in[10];

  char* ws = (char*)d_ws;
  _Float16*  xTh   = (_Float16*)(ws + OFF_XT);
  _Float16*  wB    = (_Float16*)(ws + OFF_WB);
  _Float16*  wOff  = (_Float16*)(ws + OFF_WO);
  float*     bnS   = (float*)(ws + OFF_BN);
  float*     bnB   = bnS + 64;

  prep_kernel<<<217, 256, 0, stream>>>(weight, offw, modw, bias, gamma, beta,
                                       mean, var, wB, wOff, bnS, bnB);
  transpose_x_kernel<<<1152, 256, 0, stream>>>(x, xTh);
  dcn_fused_kernel<<<4608, 256, 0, stream>>>(xTh, wOff, offb, modb, wB,
                                             bnS, bnB, (float*)d_out);
}